// Round 7
// baseline (337.581 us; speedup 1.0000x reference)
//
#include <hip/hip_runtime.h>

// Problem geometry
#define BATCH 4
#define CIN   8
#define DEPTH 48
#define HGT   128
#define WID   160

#define HW    (HGT*WID)        // 20480
#define DHW   (DEPTH*HW)       // 983040
#define CDHW  (CIN*DHW)        // 7864320 (elements per batch sample)
#define NPIX  (BATCH*HW)       // 81920

#define DSPLIT 8               // waves per block; wave w handles depth chunk w
#define DCHUNK (DEPTH/DSPLIT)  // 6
#define TILES_PER_B (HW/128)   // 160 (128 px per block tile, 2 px/lane)
#define NBLK (NPIX/128)        // 640 blocks of 512 threads

typedef _Float16 half2_t __attribute__((ext_vector_type(2)));   // fdot2 operand type

static __device__ __forceinline__ float asf(unsigned int u) {
    return __builtin_bit_cast(float, u);
}
static __device__ __forceinline__ unsigned int asu(float f) {
    return __builtin_bit_cast(unsigned int, f);
}
static __device__ __forceinline__ unsigned int pkrtz_u(float a, float b) {
    return __builtin_bit_cast(unsigned int, __builtin_amdgcn_cvt_pkrtz(a, b));
}
static __device__ __forceinline__ float fdot2_u(unsigned int a, unsigned int b, float c) {
    return __builtin_amdgcn_fdot2(__builtin_bit_cast(half2_t, a),
                                  __builtin_bit_cast(half2_t, b), c, false);
}
// dtype-agnostic scalar param load (wire dtype is fp32 — proven R5 vs R6; bf16 kept as failsafe)
static __device__ __forceinline__ float ldp(const void* p, int i, bool bf) {
    if (bf) {
        unsigned int u = ((const unsigned short*)p)[i];
        return asf(u << 16);
    }
    return ((const float*)p)[i];
}

// Single fused kernel: inline dtype probe -> per-wave BN fold -> 6 depth-slices of the
// 3-layer MLP (f16 dot2) -> LDS max-reduce across 8 waves -> sigmoid -> store.
__global__ __launch_bounds__(512, 2)
void fused_kernel(const void* __restrict__ xv,
                  const void* __restrict__ w0, const void* __restrict__ g0,
                  const void* __restrict__ b0, const void* __restrict__ m0,
                  const void* __restrict__ v0, const void* __restrict__ w1,
                  const void* __restrict__ g1, const void* __restrict__ b1,
                  const void* __restrict__ m1, const void* __restrict__ v1,
                  const void* __restrict__ w2, const void* __restrict__ b2,
                  void* __restrict__ out)
{
    __shared__ float2 sm[DSPLIT][64];

    const unsigned int* xb = (const unsigned int*)xv;  // bf16 view: dword = 2 adjacent px of one ch
    const float2*      xf = (const float2*)xv;         // fp32 view: float2 = 2 adjacent px

    const int tid  = threadIdx.x;
    const int wave = tid >> 6;
    const int lane = tid & 63;
    const int tile = blockIdx.x;
    const int b    = tile / TILES_PER_B;
    const int tp   = tile % TILES_PER_B;
    const int hwp  = tp * 64 + lane;                   // pixel-pair index within image
    const unsigned bbase = (unsigned)(b * (CDHW/2)) + (unsigned)hwp;
    const int d0 = wave * DCHUNK;

    // ---- inline dtype probe: first 256 B of x (L2-broadcast, ~free). byte1 of a dword is the
    // bf16 exponent byte (hit ~95% for N(0,1)) vs fp32 mantissa bits (~6%). 64 samples, majority.
    bool bf;
    {
        unsigned int u = xb[lane];
        bool hit = (((u >> 8) & 0x78u) == 0x38u);
        unsigned long long m = __ballot(hit);
        bf = (__popcll(m) >= 32);
    }

    // ---- per-wave redundant BN fold (lanes identical; broadcast loads; once per wave) ----
    unsigned int W0p[64], W1p[64];
    float S0[16], S1[8], W2[8];
    #pragma unroll
    for (int t = 0; t < 16; ++t) {
        float sc = ldp(g0, t, bf) * rsqrtf(ldp(v0, t, bf) + 1e-5f);
        #pragma unroll
        for (int c = 0; c < 4; ++c)
            W0p[t*4 + c] = pkrtz_u(ldp(w0, t*8 + 2*c, bf) * sc,
                                   ldp(w0, t*8 + 2*c + 1, bf) * sc);
        S0[t] = ldp(b0, t, bf) - ldp(m0, t, bf) * sc;
    }
    #pragma unroll
    for (int t = 0; t < 8; ++t) {
        float sc = ldp(g1, t, bf) * rsqrtf(ldp(v1, t, bf) + 1e-5f);
        #pragma unroll
        for (int c = 0; c < 8; ++c)
            W1p[t*8 + c] = pkrtz_u(ldp(w1, t*16 + 2*c, bf) * sc,
                                   ldp(w1, t*16 + 2*c + 1, bf) * sc);
        S1[t] = ldp(b1, t, bf) - ldp(m1, t, bf) * sc;
        W2[t] = ldp(w2, t, bf);
    }
    const float B2v = ldp(b2, 0, bf);

    // ---- depth-chunk MLP, tracking max logit for 2 pixels ----
    float mA = -1e30f, mB = -1e30f;

    #pragma unroll 2
    for (int dd = 0; dd < DCHUNK; ++dd) {
        int d = d0 + dd;
        unsigned idx0 = bbase + (unsigned)(d * (HW/2));

        // per-pixel channel-pair f16x2: xA = even pixel, xB = odd pixel
        unsigned int xA[4], xB[4];
        if (bf) {
            unsigned int xd[8];
            #pragma unroll
            for (int c = 0; c < 8; ++c) xd[c] = xb[idx0 + (unsigned)(c * (DHW/2))];
            #pragma unroll
            for (int j = 0; j < 4; ++j) {
                xA[j] = pkrtz_u(asf(xd[2*j] << 16),        asf(xd[2*j+1] << 16));
                xB[j] = pkrtz_u(asf(xd[2*j] & 0xFFFF0000u), asf(xd[2*j+1] & 0xFFFF0000u));
            }
        } else {
            float2 v[8];
            #pragma unroll
            for (int c = 0; c < 8; ++c) v[c] = xf[idx0 + (unsigned)(c * (DHW/2))];
            #pragma unroll
            for (int j = 0; j < 4; ++j) {
                xA[j] = pkrtz_u(v[2*j].x, v[2*j+1].x);
                xB[j] = pkrtz_u(v[2*j].y, v[2*j+1].y);
            }
        }

        // layer 0: 8 -> 16, folded bias, relu
        float h0A[16], h0B[16];
        #pragma unroll
        for (int o = 0; o < 16; ++o) {
            float a = S0[o], c = S0[o];
            #pragma unroll
            for (int j = 0; j < 4; ++j) {
                a = fdot2_u(xA[j], W0p[o*4 + j], a);
                c = fdot2_u(xB[j], W0p[o*4 + j], c);
            }
            h0A[o] = fmaxf(a, 0.f);
            h0B[o] = fmaxf(c, 0.f);
        }
        unsigned int gA[8], gB[8];
        #pragma unroll
        for (int k = 0; k < 8; ++k) {
            gA[k] = pkrtz_u(h0A[2*k], h0A[2*k+1]);
            gB[k] = pkrtz_u(h0B[2*k], h0B[2*k+1]);
        }

        // layer 1: 16 -> 8 (+relu), layer 2: 8 -> 1 fused
        float sA = B2v, sB = B2v;
        #pragma unroll
        for (int o = 0; o < 8; ++o) {
            float a = S1[o], c = S1[o];
            #pragma unroll
            for (int k = 0; k < 8; ++k) {
                a = fdot2_u(gA[k], W1p[o*8 + k], a);
                c = fdot2_u(gB[k], W1p[o*8 + k], c);
            }
            sA = fmaf(W2[o], fmaxf(a, 0.f), sA);
            sB = fmaf(W2[o], fmaxf(c, 0.f), sB);
        }
        mA = fmaxf(mA, sA);
        mB = fmaxf(mB, sB);
    }

    // ---- cross-wave max via LDS, then sigmoid + dtype-correct store (wave 0) ----
    float2 r; r.x = mA; r.y = mB;
    sm[wave][lane] = r;
    __syncthreads();

    if (wave == 0) {
        float a = -1e30f, c = -1e30f;
        #pragma unroll
        for (int k = 0; k < DSPLIT; ++k) {
            float2 v = sm[k][lane];
            a = fmaxf(a, v.x);
            c = fmaxf(c, v.y);
        }
        // sigmoid(max) == max(sigmoid): sigmoid is monotone
        float sa = 1.0f / (1.0f + __expf(-a));
        float sc = 1.0f / (1.0f + __expf(-c));
        unsigned outIdx = (unsigned)(b * (HW/2)) + (unsigned)hwp;   // pixel-pair index
        if (bf) {
            unsigned int ua = asu(sa), uc = asu(sc);
            unsigned int ra = (ua + 0x7FFFu + ((ua >> 16) & 1u)) >> 16;   // RNE bf16
            unsigned int rc = (uc + 0x7FFFu + ((uc >> 16) & 1u)) >> 16;
            ((unsigned int*)out)[outIdx] = ra | (rc << 16);
        } else {
            float2 o; o.x = sa; o.y = sc;
            ((float2*)out)[outIdx] = o;   // fp32 wire format (proven R5-vs-R6)
        }
    }
}

extern "C" void kernel_launch(void* const* d_in, const int* in_sizes, int n_in,
                              void* d_out, int out_size, void* d_ws, size_t ws_size,
                              hipStream_t stream)
{
    fused_kernel<<<NBLK, 512, 0, stream>>>(
        d_in[0],
        d_in[1], d_in[2], d_in[3], d_in[4], d_in[5], d_in[6],
        d_in[7], d_in[8], d_in[9], d_in[10], d_in[11], d_in[12],
        d_out);
}

// Round 8
// 217.998 us; speedup vs baseline: 1.5485x; 1.5485x over previous
//
#include <hip/hip_runtime.h>

// Problem geometry
#define BATCH 4
#define CIN   8
#define DEPTH 48
#define HGT   128
#define WID   160

#define HW    (HGT*WID)        // 20480
#define DHW   (DEPTH*HW)       // 983040
#define CDHW  (CIN*DHW)        // 7864320 (elements per batch sample)
#define NPIX  (BATCH*HW)       // 81920

#define DSPLIT 8               // waves per block; wave w handles depth chunk w
#define DCHUNK (DEPTH/DSPLIT)  // 6
#define TILES_PER_B (HW/128)   // 160 (128 px per block tile, 2 px/lane)
#define NBLK (NPIX/128)        // 640 blocks of 512 threads

// LDS weight-staging layout (dword offsets within lw[])
#define LW_W0P 0     // 64 uints: f16x2 pairs, layer0 (16 o x 4 cpairs)
#define LW_S0F 64    // 16 f32 folded biases
#define LW_W1P 80    // 64 uints: f16x2 pairs, layer1 (8 o x 8 cpairs)
#define LW_S1F 144   // 8 f32
#define LW_W2F 152   // 8 f32
#define LW_B2F 160   // 1 f32
#define LW_NW  176   // padded total

typedef _Float16 half2_t __attribute__((ext_vector_type(2)));   // fdot2 operand type

static __device__ __forceinline__ float asf(unsigned int u) {
    return __builtin_bit_cast(float, u);
}
static __device__ __forceinline__ unsigned int asu(float f) {
    return __builtin_bit_cast(unsigned int, f);
}
static __device__ __forceinline__ unsigned int pkrtz_u(float a, float b) {
    return __builtin_bit_cast(unsigned int, __builtin_amdgcn_cvt_pkrtz(a, b));
}
static __device__ __forceinline__ float fdot2_u(unsigned int a, unsigned int b, float c) {
    return __builtin_amdgcn_fdot2(__builtin_bit_cast(half2_t, a),
                                  __builtin_bit_cast(half2_t, b), c, false);
}
// dtype-agnostic scalar param load (wire dtype is fp32 — proven R5-vs-R6; bf16 kept as failsafe)
static __device__ __forceinline__ float ldp(const void* p, int i, bool bf) {
    if (bf) {
        unsigned int u = ((const unsigned short*)p)[i];
        return asf(u << 16);
    }
    return ((const float*)p)[i];
}

// Single fused kernel: inline dtype probe -> wave-0 BN fold into LDS -> broadcast preload ->
// 6 depth-slices of the 3-layer MLP (f16 dot2) -> LDS max-reduce across 8 waves -> sigmoid -> store.
// waves_per_eu(2,2) pins occupancy: R7 showed the compiler otherwise flips to 4 waves/EU,
// caps VGPR at 128, and spills the 161-dword weight set to scratch (138 MB of scratch writes).
__global__ __launch_bounds__(512)
__attribute__((amdgpu_waves_per_eu(2, 2)))
void fused_kernel(const void* __restrict__ xv,
                  const void* __restrict__ w0, const void* __restrict__ g0,
                  const void* __restrict__ b0, const void* __restrict__ m0,
                  const void* __restrict__ v0, const void* __restrict__ w1,
                  const void* __restrict__ g1, const void* __restrict__ b1,
                  const void* __restrict__ m1, const void* __restrict__ v1,
                  const void* __restrict__ w2, const void* __restrict__ b2,
                  void* __restrict__ out)
{
    __shared__ float lw[LW_NW];          // folded weights (staged by wave 0)
    __shared__ float2 sm[DSPLIT][64];    // cross-wave max reduce

    const unsigned int* xb = (const unsigned int*)xv;  // bf16 view: dword = 2 adjacent px of one ch
    const float2*      xf = (const float2*)xv;         // fp32 view: float2 = 2 adjacent px

    const int tid  = threadIdx.x;
    const int wave = tid >> 6;
    const int lane = tid & 63;
    const int tile = blockIdx.x;
    const int b    = tile / TILES_PER_B;
    const int tp   = tile % TILES_PER_B;
    const int hwp  = tp * 64 + lane;                   // pixel-pair index within image
    const unsigned bbase = (unsigned)(b * (CDHW/2)) + (unsigned)hwp;
    const int d0 = wave * DCHUNK;

    // ---- inline dtype probe: first 256 B of x (L2-broadcast). byte1 of a dword is the bf16
    // exponent byte (hit ~95% for N(0,1)) vs fp32 mantissa bits (~6%). 64 samples, majority.
    bool bf;
    {
        unsigned int u = xb[lane];
        bool hit = (((u >> 8) & 0x78u) == 0x38u);
        unsigned long long m = __ballot(hit);
        bf = (__popcll(m) >= 32);
    }

    // ---- wave-0 BN fold into LDS (R6 prep body, LDS-targeted) ----
    if (wave == 0) {
        unsigned int* lwu = (unsigned int*)lw;
        int t = lane;
        if (t < 16) {
            float sc = ldp(g0, t, bf) * rsqrtf(ldp(v0, t, bf) + 1e-5f);
            for (int c = 0; c < 4; ++c)
                lwu[LW_W0P + t*4 + c] = pkrtz_u(ldp(w0, t*8 + 2*c, bf) * sc,
                                                ldp(w0, t*8 + 2*c + 1, bf) * sc);
            lw[LW_S0F + t] = ldp(b0, t, bf) - ldp(m0, t, bf) * sc;
        }
        if (t < 8) {
            float sc = ldp(g1, t, bf) * rsqrtf(ldp(v1, t, bf) + 1e-5f);
            for (int c = 0; c < 8; ++c)
                lwu[LW_W1P + t*8 + c] = pkrtz_u(ldp(w1, t*16 + 2*c, bf) * sc,
                                                ldp(w1, t*16 + 2*c + 1, bf) * sc);
            lw[LW_S1F + t] = ldp(b1, t, bf) - ldp(m1, t, bf) * sc;
            lw[LW_W2F + t] = ldp(w2, t, bf);
        }
        if (t == 0) lw[LW_B2F] = ldp(b2, 0, bf);
    }
    __syncthreads();

    // ---- broadcast preload LDS -> VGPRs (uniform addresses: ds_read broadcasts, no conflict) ----
    unsigned int W0p[64], W1p[64];
    float S0[16], S1[8], W2[8];
    {
        const unsigned int* lwu = (const unsigned int*)lw;
        const uint4* q0 = (const uint4*)(lwu + LW_W0P);
        #pragma unroll
        for (int i = 0; i < 16; ++i) { uint4 q = q0[i]; W0p[4*i]=q.x; W0p[4*i+1]=q.y; W0p[4*i+2]=q.z; W0p[4*i+3]=q.w; }
        const uint4* q1 = (const uint4*)(lwu + LW_W1P);
        #pragma unroll
        for (int i = 0; i < 16; ++i) { uint4 q = q1[i]; W1p[4*i]=q.x; W1p[4*i+1]=q.y; W1p[4*i+2]=q.z; W1p[4*i+3]=q.w; }
        const float4* qs = (const float4*)(lw + LW_S0F);
        #pragma unroll
        for (int i = 0; i < 4; ++i) { float4 f = qs[i]; S0[4*i]=f.x; S0[4*i+1]=f.y; S0[4*i+2]=f.z; S0[4*i+3]=f.w; }
        const float4* qt = (const float4*)(lw + LW_S1F);
        #pragma unroll
        for (int i = 0; i < 2; ++i) { float4 f = qt[i]; S1[4*i]=f.x; S1[4*i+1]=f.y; S1[4*i+2]=f.z; S1[4*i+3]=f.w; }
        const float4* qw = (const float4*)(lw + LW_W2F);
        #pragma unroll
        for (int i = 0; i < 2; ++i) { float4 f = qw[i]; W2[4*i]=f.x; W2[4*i+1]=f.y; W2[4*i+2]=f.z; W2[4*i+3]=f.w; }
    }
    const float B2v = lw[LW_B2F];

    // ---- depth-chunk MLP, tracking max logit for 2 pixels ----
    float mA = -1e30f, mB = -1e30f;

    #pragma unroll 2
    for (int dd = 0; dd < DCHUNK; ++dd) {
        int d = d0 + dd;
        unsigned idx0 = bbase + (unsigned)(d * (HW/2));

        // per-pixel channel-pair f16x2: xA = even pixel, xB = odd pixel
        unsigned int xA[4], xB[4];
        if (bf) {
            unsigned int xd[8];
            #pragma unroll
            for (int c = 0; c < 8; ++c) xd[c] = xb[idx0 + (unsigned)(c * (DHW/2))];
            #pragma unroll
            for (int j = 0; j < 4; ++j) {
                xA[j] = pkrtz_u(asf(xd[2*j] << 16),        asf(xd[2*j+1] << 16));
                xB[j] = pkrtz_u(asf(xd[2*j] & 0xFFFF0000u), asf(xd[2*j+1] & 0xFFFF0000u));
            }
        } else {
            float2 v[8];
            #pragma unroll
            for (int c = 0; c < 8; ++c) v[c] = xf[idx0 + (unsigned)(c * (DHW/2))];
            #pragma unroll
            for (int j = 0; j < 4; ++j) {
                xA[j] = pkrtz_u(v[2*j].x, v[2*j+1].x);
                xB[j] = pkrtz_u(v[2*j].y, v[2*j+1].y);
            }
        }

        // layer 0: 8 -> 16, folded bias, relu
        float h0A[16], h0B[16];
        #pragma unroll
        for (int o = 0; o < 16; ++o) {
            float a = S0[o], c = S0[o];
            #pragma unroll
            for (int j = 0; j < 4; ++j) {
                a = fdot2_u(xA[j], W0p[o*4 + j], a);
                c = fdot2_u(xB[j], W0p[o*4 + j], c);
            }
            h0A[o] = fmaxf(a, 0.f);
            h0B[o] = fmaxf(c, 0.f);
        }
        unsigned int gA[8], gB[8];
        #pragma unroll
        for (int k = 0; k < 8; ++k) {
            gA[k] = pkrtz_u(h0A[2*k], h0A[2*k+1]);
            gB[k] = pkrtz_u(h0B[2*k], h0B[2*k+1]);
        }

        // layer 1: 16 -> 8 (+relu), layer 2: 8 -> 1 fused
        float sA = B2v, sB = B2v;
        #pragma unroll
        for (int o = 0; o < 8; ++o) {
            float a = S1[o], c = S1[o];
            #pragma unroll
            for (int k = 0; k < 8; ++k) {
                a = fdot2_u(gA[k], W1p[o*8 + k], a);
                c = fdot2_u(gB[k], W1p[o*8 + k], c);
            }
            sA = fmaf(W2[o], fmaxf(a, 0.f), sA);
            sB = fmaf(W2[o], fmaxf(c, 0.f), sB);
        }
        mA = fmaxf(mA, sA);
        mB = fmaxf(mB, sB);
    }

    // ---- cross-wave max via LDS, then sigmoid + dtype-correct store (wave 0) ----
    float2 r; r.x = mA; r.y = mB;
    sm[wave][lane] = r;
    __syncthreads();

    if (wave == 0) {
        float a = -1e30f, c = -1e30f;
        #pragma unroll
        for (int k = 0; k < DSPLIT; ++k) {
            float2 v = sm[k][lane];
            a = fmaxf(a, v.x);
            c = fmaxf(c, v.y);
        }
        // sigmoid(max) == max(sigmoid): sigmoid is monotone
        float sa = 1.0f / (1.0f + __expf(-a));
        float sc = 1.0f / (1.0f + __expf(-c));
        unsigned outIdx = (unsigned)(b * (HW/2)) + (unsigned)hwp;   // pixel-pair index
        if (bf) {
            unsigned int ua = asu(sa), uc = asu(sc);
            unsigned int ra = (ua + 0x7FFFu + ((ua >> 16) & 1u)) >> 16;   // RNE bf16
            unsigned int rc = (uc + 0x7FFFu + ((uc >> 16) & 1u)) >> 16;
            ((unsigned int*)out)[outIdx] = ra | (rc << 16);
        } else {
            float2 o; o.x = sa; o.y = sc;
            ((float2*)out)[outIdx] = o;   // fp32 wire format (proven R5-vs-R6)
        }
    }
}

extern "C" void kernel_launch(void* const* d_in, const int* in_sizes, int n_in,
                              void* d_out, int out_size, void* d_ws, size_t ws_size,
                              hipStream_t stream)
{
    fused_kernel<<<NBLK, 512, 0, stream>>>(
        d_in[0],
        d_in[1], d_in[2], d_in[3], d_in[4], d_in[5], d_in[6],
        d_in[7], d_in[8], d_in[9], d_in[10], d_in[11], d_in[12],
        d_out);
}